// Round 2
// baseline (79.394 us; speedup 1.0000x reference)
//
#include <hip/hip_runtime.h>

// ST-BIF multi-step neuron, collapsed to an elementwise kernel.
//
// Exactness argument (unchanged): with T=8 steps and level=8, the spike
// counter can never hit the clamp (|cnt| <= t-1 <= 7 < 8 before any step),
// and fire_pos/fire_neg are mutually exclusive (h >= vth vs h < 0). So cnt
// and its 4 ops/step are dead. Each step is:
//   h = v + x; d = (h>=vth) ? vth : (h<0 ? -vth : 0); v = h - d; acc += d;
// bit-exact vs the reference scan (d == spike*vth exactly, same FP order).
//
// Memory-bound target: 2 x 25.7 MB traffic -> ~8 us at 6.3 TB/s.
// Round 1 fix: __builtin_nontemporal_store requires a clang vector type,
// not HIP's float4 struct -> use ext_vector_type(4) float throughout the
// vector path. Otherwise identical to round 0's plan: grid-stride capped at
// 2048 blocks, nontemporal stores (out is write-only; don't evict x from
// L2/L3), tail folded into the single kernel (one graph node).

constexpr int T_STEPS = 8;

typedef float f32x4 __attribute__((ext_vector_type(4)));

__device__ __forceinline__ float stbif_elem(float x, float vth) {
    float v = 0.0f, acc = 0.0f;
#pragma unroll
    for (int t = 0; t < T_STEPS; ++t) {
        float h = v + x;
        // fire_pos priority; mutually exclusive with fire_neg, cnt clamp dead.
        float d = (h >= vth) ? vth : ((h < 0.0f) ? -vth : 0.0f);
        v = h - d;
        acc += d;
    }
    return acc * 0.125f;  // /8 exact (power of two)
}

__global__ void __launch_bounds__(256) stbif_kernel(
    const f32x4* __restrict__ x4, const float* __restrict__ vth_ptr,
    f32x4* __restrict__ out4,
    const float* __restrict__ x, float* __restrict__ out,
    int n4, int n) {
    const float vth = *vth_ptr;  // uniform scalar load, L1-resident
    const int stride = gridDim.x * blockDim.x;
    int gid = blockIdx.x * blockDim.x + threadIdx.x;

    // main body: 16 B/lane, coalesced, grid-stride
    for (int i = gid; i < n4; i += stride) {
        f32x4 xv = x4[i];
        f32x4 ov;
        ov.x = stbif_elem(xv.x, vth);
        ov.y = stbif_elem(xv.y, vth);
        ov.z = stbif_elem(xv.z, vth);
        ov.w = stbif_elem(xv.w, vth);
        __builtin_nontemporal_store(ov, &out4[i]);
    }

    // scalar tail (n % 4 elements; zero for the bench shape but kept correct)
    for (int i = n4 * 4 + gid; i < n; i += stride) {
        __builtin_nontemporal_store(stbif_elem(x[i], vth), &out[i]);
    }
}

extern "C" void kernel_launch(void* const* d_in, const int* in_sizes, int n_in,
                              void* d_out, int out_size, void* d_ws, size_t ws_size,
                              hipStream_t stream) {
    const float* x   = (const float*)d_in[0];
    const float* vth = (const float*)d_in[1];
    float* out = (float*)d_out;
    int n = in_sizes[0];

    int n4 = n / 4;
    int work = (n4 > 0) ? n4 : n;
    int blocks = (work + 255) / 256;
    if (blocks > 2048) blocks = 2048;  // G11: cap + grid-stride
    if (blocks < 1) blocks = 1;

    stbif_kernel<<<blocks, 256, 0, stream>>>(
        (const f32x4*)x, vth, (f32x4*)out, x, out, n4, n);
}